// Round 17
// baseline (199.374 us; speedup 1.0000x reference)
//
#include <hip/hip_runtime.h>
#include <stdint.h>
#include <math.h>

typedef unsigned long long u64;
typedef float f4 __attribute__((ext_vector_type(4)));

#define K1_THREADS 512
#define K1_WAVES 8
#define K1_BATCH 4
#define SPLIT 4
#define NBINS 2048
#define BIN_SHIFT 21
#define CAND_MAX 1024
#define MAXK 64

// order-preserving fp32 -> uint32 key
__device__ __forceinline__ uint32_t fkey(float f) {
    uint32_t b = __float_as_uint(f);
    return b ^ (uint32_t)(((int32_t)b >> 31) | 0x80000000);
}
__device__ __forceinline__ float fval(uint32_t k) {
    uint32_t b = (k & 0x80000000u) ? (k & 0x7FFFFFFFu) : ~k;
    return __uint_as_float(b);
}

// BRANCHLESS sorted-4 insert (t0>=t1>=t2>=t3, packed u64 key|~idx).
#define INSB(vf, gidx) do {                                                    \
    u64 c_ = ((u64)fkey(vf) << 32) | (uint32_t)~(uint32_t)(gidx);              \
    bool g0_ = c_ > t0; u64 n0_ = g0_ ? c_ : t0; c_ = g0_ ? t0 : c_; t0 = n0_; \
    bool g1_ = c_ > t1; u64 n1_ = g1_ ? c_ : t1; c_ = g1_ ? t1 : c_; t1 = n1_; \
    bool g2_ = c_ > t2; u64 n2_ = g2_ ? c_ : t2; c_ = g2_ ? t2 : c_; t2 = n2_; \
    bool g3_ = c_ > t3; u64 n3_ = g3_ ? c_ : t3; c_ = g3_ ? t3 : c_; t3 = n3_; \
    uint32_t dk_ = (uint32_t)(c_ >> 32);                                       \
    dkey = (dk_ > dkey) ? dk_ : dkey;                                          \
} while (0)

// ========== fused kernel: slice top-K, last slice-block merges+samples ======
__global__ __launch_bounds__(K1_THREADS, 8) void fused_sampler_kernel(
    const float* __restrict__ logits,
    const float* __restrict__ temperature,
    const float* __restrict__ top_p,
    const int* __restrict__ token_lengths,
    const int* __restrict__ top_k_ptr,
    int* __restrict__ out,
    int* __restrict__ ctr,          // B counters (zeroed per launch)
    u64* __restrict__ slices,       // B*SPLIT*MAXK slice results
    int V)
{
    const int row = blockIdx.x / SPLIT;
    const int sl  = blockIdx.x % SPLIT;
    const int tid = threadIdx.x;
    const int lane = tid & 63;
    const int wid  = tid >> 6;
    int K = *top_k_ptr;
    if (K < 1) K = 1;
    if (K > MAXK) K = MAXK;

    __shared__ u64 s_cand4[K1_THREADS * 4];     // 16 KB
    __shared__ uint32_t s_hist[NBINS];          //  8 KB
    __shared__ u64 s_cand[CAND_MAX];            //  8 KB
    __shared__ u64 s_top[MAXK];
    __shared__ uint32_t s_wsum[K1_WAVES], s_wtail[K1_WAVES];
    __shared__ int s_T, s_cnt, s_merge;
    __shared__ float s_vals[MAXK];
    __shared__ int s_idx[MAXK], s_slot[MAXK];

    for (int i = tid; i < NBINS; i += K1_THREADS) s_hist[i] = 0u;
    if (tid == 0) s_cnt = 0;

    const float* rowbase = logits + (size_t)row * (size_t)V;
    const f4* rowp = reinterpret_cast<const f4*>(rowbase);
    const int nv = V >> 2;
    const int snf = (nv + SPLIT - 1) / SPLIT;
    const int f0 = sl * snf;
    const int f1 = (f0 + snf < nv) ? (f0 + snf) : nv;

    // ---- stream the slice: nontemporal loads + branchless top-4 ----
    u64 t0 = 0ull, t1 = 0ull, t2 = 0ull, t3 = 0ull;
    uint32_t dkey = 0u;
    const int step = K1_THREADS * K1_BATCH;
    const int niter = (f1 - f0) / step;          // full, unconditional iters

    for (int it = 0; it < niter; ++it) {
        const int j0 = f0 + it * step + tid;
        f4 x[K1_BATCH];
        #pragma unroll
        for (int b = 0; b < K1_BATCH; ++b)
            x[b] = __builtin_nontemporal_load(rowp + (j0 + b * K1_THREADS));
        #pragma unroll
        for (int b = 0; b < K1_BATCH; ++b) {
            const int g = (j0 + b * K1_THREADS) << 2;
            INSB(x[b][0], g + 0);
            INSB(x[b][1], g + 1);
            INSB(x[b][2], g + 2);
            INSB(x[b][3], g + 3);
        }
    }
    for (int j = f0 + niter * step + tid; j < f1; j += K1_THREADS) {
        f4 x = __builtin_nontemporal_load(rowp + j);
        const int g = j << 2;
        INSB(x[0], g + 0);
        INSB(x[1], g + 1);
        INSB(x[2], g + 2);
        INSB(x[3], g + 3);
    }
    __syncthreads();      // hist zeros visible

    // ---- publish candidates + tiny histogram ----
    s_cand4[tid * 4 + 0] = t0;
    s_cand4[tid * 4 + 1] = t1;
    s_cand4[tid * 4 + 2] = t2;
    s_cand4[tid * 4 + 3] = t3;
    atomicAdd(&s_hist[(uint32_t)(t0 >> 32) >> BIN_SHIFT], 1u);
    atomicAdd(&s_hist[(uint32_t)(t1 >> 32) >> BIN_SHIFT], 1u);
    atomicAdd(&s_hist[(uint32_t)(t2 >> 32) >> BIN_SHIFT], 1u);
    atomicAdd(&s_hist[(uint32_t)(t3 >> 32) >> BIN_SHIFT], 1u);
    __syncthreads();

    // ---- threshold bin T: suffix count >= K ----
    const int CH = NBINS / K1_THREADS;   // 4
    uint32_t cs = 0;
    {
        const int b0 = tid * CH;
        #pragma unroll
        for (int b = 0; b < CH; ++b) cs += s_hist[b0 + b];
    }
    uint32_t suf = cs;
    #pragma unroll
    for (int off = 1; off < 64; off <<= 1) {
        uint32_t o = __shfl_down(suf, off, 64);
        suf += (lane + off < 64) ? o : 0u;
    }
    if (lane == 0) s_wsum[wid] = suf;
    __syncthreads();
    if (wid == 0 && lane < K1_WAVES) {
        uint32_t t = s_wsum[lane];
        uint32_t s = t;
        #pragma unroll
        for (int off = 1; off < K1_WAVES; off <<= 1) {
            uint32_t o = __shfl_down(s, off, 64);
            s += (lane + off < K1_WAVES) ? o : 0u;
        }
        s_wtail[lane] = s - t;
    }
    __syncthreads();
    {
        uint32_t sufg = suf + s_wtail[wid];
        uint32_t sufn = sufg - cs;
        if (sufg >= (uint32_t)K && sufn < (uint32_t)K) {
            uint32_t acc = sufn;
            int T = tid * CH;
            for (int b = tid * CH + CH - 1; b >= tid * CH; --b) {
                acc += s_hist[b];
                if (acc >= (uint32_t)K) { T = b; break; }
            }
            s_T = T;
        }
    }
    __syncthreads();

    // ---- collect candidates with bin >= T ----
    const uint32_t T = (uint32_t)s_T;
    #pragma unroll
    for (int r = 0; r < 4; ++r) {
        u64 c = s_cand4[tid * 4 + r];
        if (((uint32_t)(c >> 32) >> BIN_SHIFT) >= T) {
            int p = atomicAdd(&s_cnt, 1);
            if (p < CAND_MAX) s_cand[p] = c;
        }
    }
    __syncthreads();

    // ---- parallel rank-based top-K (packed order: value desc, idx asc) ----
    {
        const int M = (s_cnt < CAND_MAX) ? s_cnt : CAND_MAX;
        for (int t = tid; t < M; t += K1_THREADS) {
            const u64 mine = s_cand[t];
            int rank = 0;
            for (int j = 0; j < M; ++j) rank += (s_cand[j] > mine) ? 1 : 0;
            if (rank < MAXK) s_top[rank] = mine;
        }
    }
    __syncthreads();

    // ---- exactness guard: any thread dropped a key >= kth key? ----
    const u64 kth = s_top[K - 1];
    const int bad = (dkey >= (uint32_t)(kth >> 32)) ? 1 : 0;
    if (__syncthreads_or(bad)) {
        if (tid == 0) s_cnt = 0;
        __syncthreads();
        const int e0 = f0 << 2;
        const int e1 = f1 << 2;
        for (int e = e0 + tid; e < e1; e += K1_THREADS) {
            u64 p = ((u64)fkey(rowbase[e]) << 32) | (uint32_t)~(uint32_t)e;
            if (p >= kth) {
                int q = atomicAdd(&s_cnt, 1);
                if (q < CAND_MAX) s_cand[q] = p;
            }
        }
        __syncthreads();
        const int M2 = (s_cnt < CAND_MAX) ? s_cnt : CAND_MAX;
        for (int t = tid; t < M2; t += K1_THREADS) {
            const u64 mine = s_cand[t];
            int rank = 0;
            for (int j = 0; j < M2; ++j) rank += (s_cand[j] > mine) ? 1 : 0;
            if (rank < MAXK) s_top[rank] = mine;
        }
        __syncthreads();
    }

    if (tid < K) slices[(size_t)blockIdx.x * MAXK + tid] = s_top[tid];
    __syncthreads();                 // slice writes issued by all threads

    // ---- completion handshake: 4th finisher of this row does the merge ----
    if (tid == 0) {
        __threadfence();             // release slice writes to device scope
        int old = __hip_atomic_fetch_add(&ctr[row], 1, __ATOMIC_ACQ_REL,
                                         __HIP_MEMORY_SCOPE_AGENT);
        s_merge = (old == SPLIT - 1) ? 1 : 0;
    }
    __syncthreads();
    if (!s_merge) return;
    __threadfence();                 // acquire other slices' writes

    // ================= merge + sampler math (validated R6 body) ============
    const int M = SPLIT * K;

    if (tid < M) {
        const int s = tid / K, k = tid - s * K;
        s_cand[tid] = slices[(size_t)(row * SPLIT + s) * MAXK + k];
    }
    __syncthreads();

    if (tid < M) {
        const u64 mine = s_cand[tid];
        int rank = 0;
        for (int j = 0; j < M; ++j) rank += (s_cand[j] > mine) ? 1 : 0;
        if (rank < MAXK) {
            s_idx[rank]  = (int)(~(uint32_t)mine);
            s_vals[rank] = fval((uint32_t)(mine >> 32));
        }
    }
    __syncthreads();

    if (tid >= 64) return;          // no __syncthreads below this point

    const float temp = temperature[row];
    const float tp   = top_p[row];

    // stage 1 softmax over K scaled values (lane i owns slot i)
    const float a0 = s_vals[0] / temp;
    float e = 0.f;
    int myidx = -1;
    if (tid < K) {
        myidx = s_idx[tid];
        e = expf(s_vals[tid] / temp - a0);
    }
    float sum = e;
    #pragma unroll
    for (int off = 1; off < 64; off <<= 1) sum += __shfl_xor(sum, off, 64);
    const float p1 = e / sum;

    // suffix-inclusive cumsum: cs_i = sum_{j>=i} p1_j
    float csf = p1;
    #pragma unroll
    for (int off = 1; off < 64; off <<= 1) {
        float o = __shfl_down(csf, off, 64);
        csf += (tid + off < 64) ? o : 0.f;
    }
    const float lim = 1.0f - tp;
    const bool keep = (tid < K) && (tid == 0 || csf > lim);
    const int S = __popcll(__ballot(keep));   // survivors = descending prefix [0,S)

    // stage 2 re-softmax over survivors
    float e2 = (tid < S) ? e : 0.f;
    float sum2 = e2;
    #pragma unroll
    for (int off = 1; off < 64; off <<= 1) sum2 += __shfl_xor(sum2, off, 64);
    const float p2 = e2 / sum2;

    // EOS rule
    const bool is_eos = (tid < S) && (myidx == 2);
    float eosp = is_eos ? p2 : 0.f;
    #pragma unroll
    for (int off = 1; off < 64; off <<= 1) eosp += __shfl_xor(eosp, off, 64);
    const bool has_eos = (__ballot(is_eos) != 0ull);
    const float eth = fmaxf(eosp / 100.0f, 0.005f);

    // slot indices: survivors keep token idx; padding = smallest absent ints
    if (tid < S) s_slot[tid] = myidx;
    __builtin_amdgcn_wave_barrier();
    if (tid == 0) {
        u64 m0 = 0ull, m1 = 0ull;
        for (int i = 0; i < S; ++i) {
            int id = s_idx[i];
            if (id < 64) m0 |= 1ull << id;
            else if (id < 128) m1 |= 1ull << (id - 64);
        }
        int nxt = 0;
        for (int i = S; i < K; ++i) {
            while ((nxt < 64) ? ((m0 >> nxt) & 1ull) : ((m1 >> (nxt - 64)) & 1ull)) nxt++;
            s_slot[i] = nxt++;
        }
    }
    __builtin_amdgcn_wave_barrier();

    // length softmax over all K slots
    float len = -INFINITY;
    if (tid < K) {
        int id = s_slot[tid];
        id = (id < 0) ? 0 : ((id >= V) ? V - 1 : id);
        len = (float)token_lengths[id];
    }
    float lmax = len;
    #pragma unroll
    for (int off = 1; off < 64; off <<= 1) lmax = fmaxf(lmax, __shfl_xor(lmax, off, 64));
    float el = (tid < K) ? expf(len - lmax) : 0.f;
    float lsum = el;
    #pragma unroll
    for (int off = 1; off < 64; off <<= 1) lsum += __shfl_xor(lsum, off, 64);
    const float ls = el / lsum;

    // mix + masks + first-occurrence argmax
    float mix = -INFINITY;
    if (tid < S) {
        mix = 0.5f * p2 + 0.5f * ls;
        if (!(p2 >= 0.001f)) mix = -INFINITY;
        if (has_eos && !(p2 >= eth)) mix = -INFINITY;
    }
    float bm = mix; int bi = tid;
    #pragma unroll
    for (int off = 1; off < 64; off <<= 1) {
        float om = __shfl_xor(bm, off, 64);
        int   oi = __shfl_xor(bi, off, 64);
        if (om > bm || (om == bm && oi < bi)) { bm = om; bi = oi; }
    }

    if (tid == 0) {
        int chosen = s_slot[bi];
        if (temp < 1e-5f) chosen = s_idx[0];   // greedy branch
        out[row] = chosen;
    }
}

extern "C" void kernel_launch(void* const* d_in, const int* in_sizes, int n_in,
                              void* d_out, int out_size, void* d_ws, size_t ws_size,
                              hipStream_t stream) {
    const float* logits        = (const float*)d_in[0];
    const float* temperature   = (const float*)d_in[1];
    const float* top_p         = (const float*)d_in[2];
    const int*   token_lengths = (const int*)d_in[3];
    const int*   top_k_ptr     = (const int*)d_in[4];
    int* outp = (int*)d_out;

    const int B = in_sizes[1];   // temperature length
    const int V = in_sizes[3];   // token_lengths length

    int* ctr    = (int*)d_ws;                          // B counters (1 KB)
    u64* slices = (u64*)((char*)d_ws + 1024);          // B*SPLIT*MAXK u64

    hipMemsetAsync(ctr, 0, (size_t)B * sizeof(int), stream);
    fused_sampler_kernel<<<B * SPLIT, K1_THREADS, 0, stream>>>(
        logits, temperature, top_p, token_lengths, top_k_ptr,
        outp, ctr, slices, V);
}

// Round 18
// 49.113 us; speedup vs baseline: 4.0595x; 4.0595x over previous
//
#include <hip/hip_runtime.h>
#include <stdint.h>
#include <math.h>

typedef unsigned long long u64;
typedef float f4 __attribute__((ext_vector_type(4)));

#define K1_THREADS 512
#define K1_WAVES 8
#define K1_BATCH 4
#define SPLIT 4
#define NBINS 2048
#define BIN_SHIFT 21
#define CAND_MAX 1024
#define MAXK 64

// order-preserving fp32 -> uint32 key
__device__ __forceinline__ uint32_t fkey(float f) {
    uint32_t b = __float_as_uint(f);
    return b ^ (uint32_t)(((int32_t)b >> 31) | 0x80000000);
}
__device__ __forceinline__ float fval(uint32_t k) {
    uint32_t b = (k & 0x80000000u) ? (k & 0x7FFFFFFFu) : ~k;
    return __uint_as_float(b);
}

// BRANCHLESS sorted-4 insert (t0>=t1>=t2>=t3, packed u64 key|~idx).
#define INSB(vf, gidx) do {                                                    \
    u64 c_ = ((u64)fkey(vf) << 32) | (uint32_t)~(uint32_t)(gidx);              \
    bool g0_ = c_ > t0; u64 n0_ = g0_ ? c_ : t0; c_ = g0_ ? t0 : c_; t0 = n0_; \
    bool g1_ = c_ > t1; u64 n1_ = g1_ ? c_ : t1; c_ = g1_ ? t1 : c_; t1 = n1_; \
    bool g2_ = c_ > t2; u64 n2_ = g2_ ? c_ : t2; c_ = g2_ ? t2 : c_; t2 = n2_; \
    bool g3_ = c_ > t3; u64 n3_ = g3_ ? c_ : t3; c_ = g3_ ? t3 : c_; t3 = n3_; \
    uint32_t dk_ = (uint32_t)(c_ >> 32);                                       \
    dkey = (dk_ > dkey) ? dk_ : dkey;                                          \
} while (0)

// ================= kernel 1: exact top-K of one row-slice =================
__global__ __launch_bounds__(K1_THREADS, 8) void topk_slice_kernel(
    const float* __restrict__ logits,
    const int* __restrict__ top_k_ptr,
    u64* __restrict__ ws, int V)
{
    const int row = blockIdx.x / SPLIT;
    const int sl  = blockIdx.x % SPLIT;
    const int tid = threadIdx.x;
    const int lane = tid & 63;
    const int wid  = tid >> 6;
    int K = *top_k_ptr;
    if (K < 1) K = 1;
    if (K > MAXK) K = MAXK;

    __shared__ u64 s_cand4[K1_THREADS * 4];     // 16 KB
    __shared__ uint32_t s_hist[NBINS];          //  8 KB
    __shared__ u64 s_cand[CAND_MAX];            //  8 KB
    __shared__ u64 s_top[MAXK];
    __shared__ uint32_t s_wsum[K1_WAVES], s_wtail[K1_WAVES];
    __shared__ int s_T, s_cnt;

    for (int i = tid; i < NBINS; i += K1_THREADS) s_hist[i] = 0u;
    if (tid == 0) s_cnt = 0;

    const float* rowbase = logits + (size_t)row * (size_t)V;
    const f4* rowp = reinterpret_cast<const f4*>(rowbase);
    const int nv = V >> 2;
    const int snf = (nv + SPLIT - 1) / SPLIT;
    const int f0 = sl * snf;
    const int f1 = (f0 + snf < nv) ? (f0 + snf) : nv;

    // ---- stream the slice: nontemporal loads (no L2 allocation) + top-4 ----
    u64 t0 = 0ull, t1 = 0ull, t2 = 0ull, t3 = 0ull;
    uint32_t dkey = 0u;
    const int step = K1_THREADS * K1_BATCH;
    const int niter = (f1 - f0) / step;          // full, unconditional iters

    for (int it = 0; it < niter; ++it) {
        const int j0 = f0 + it * step + tid;
        f4 x[K1_BATCH];
        #pragma unroll
        for (int b = 0; b < K1_BATCH; ++b)
            x[b] = __builtin_nontemporal_load(rowp + (j0 + b * K1_THREADS));
        #pragma unroll
        for (int b = 0; b < K1_BATCH; ++b) {
            const int g = (j0 + b * K1_THREADS) << 2;
            INSB(x[b][0], g + 0);
            INSB(x[b][1], g + 1);
            INSB(x[b][2], g + 2);
            INSB(x[b][3], g + 3);
        }
    }
    // epilogue: remaining (< step) float4s, in-bounds strided
    for (int j = f0 + niter * step + tid; j < f1; j += K1_THREADS) {
        f4 x = __builtin_nontemporal_load(rowp + j);
        const int g = j << 2;
        INSB(x[0], g + 0);
        INSB(x[1], g + 1);
        INSB(x[2], g + 2);
        INSB(x[3], g + 3);
    }
    __syncthreads();      // hist zeros visible

    // ---- publish candidates + tiny histogram ----
    s_cand4[tid * 4 + 0] = t0;
    s_cand4[tid * 4 + 1] = t1;
    s_cand4[tid * 4 + 2] = t2;
    s_cand4[tid * 4 + 3] = t3;
    atomicAdd(&s_hist[(uint32_t)(t0 >> 32) >> BIN_SHIFT], 1u);
    atomicAdd(&s_hist[(uint32_t)(t1 >> 32) >> BIN_SHIFT], 1u);
    atomicAdd(&s_hist[(uint32_t)(t2 >> 32) >> BIN_SHIFT], 1u);
    atomicAdd(&s_hist[(uint32_t)(t3 >> 32) >> BIN_SHIFT], 1u);
    __syncthreads();

    // ---- threshold bin T: suffix count >= K ----
    const int CH = NBINS / K1_THREADS;   // 4
    uint32_t cs = 0;
    {
        const int b0 = tid * CH;
        #pragma unroll
        for (int b = 0; b < CH; ++b) cs += s_hist[b0 + b];
    }
    uint32_t suf = cs;
    #pragma unroll
    for (int off = 1; off < 64; off <<= 1) {
        uint32_t o = __shfl_down(suf, off, 64);
        suf += (lane + off < 64) ? o : 0u;
    }
    if (lane == 0) s_wsum[wid] = suf;
    __syncthreads();
    if (wid == 0 && lane < K1_WAVES) {
        uint32_t t = s_wsum[lane];
        uint32_t s = t;
        #pragma unroll
        for (int off = 1; off < K1_WAVES; off <<= 1) {
            uint32_t o = __shfl_down(s, off, 64);
            s += (lane + off < K1_WAVES) ? o : 0u;
        }
        s_wtail[lane] = s - t;
    }
    __syncthreads();
    {
        uint32_t sufg = suf + s_wtail[wid];
        uint32_t sufn = sufg - cs;
        if (sufg >= (uint32_t)K && sufn < (uint32_t)K) {
            uint32_t acc = sufn;
            int T = tid * CH;
            for (int b = tid * CH + CH - 1; b >= tid * CH; --b) {
                acc += s_hist[b];
                if (acc >= (uint32_t)K) { T = b; break; }
            }
            s_T = T;
        }
    }
    __syncthreads();

    // ---- collect candidates with bin >= T ----
    const uint32_t T = (uint32_t)s_T;
    #pragma unroll
    for (int r = 0; r < 4; ++r) {
        u64 c = s_cand4[tid * 4 + r];
        if (((uint32_t)(c >> 32) >> BIN_SHIFT) >= T) {
            int p = atomicAdd(&s_cnt, 1);
            if (p < CAND_MAX) s_cand[p] = c;
        }
    }
    __syncthreads();

    // ---- parallel rank-based top-K (packed order: value desc, idx asc) ----
    {
        const int M = (s_cnt < CAND_MAX) ? s_cnt : CAND_MAX;
        for (int t = tid; t < M; t += K1_THREADS) {
            const u64 mine = s_cand[t];
            int rank = 0;
            for (int j = 0; j < M; ++j) rank += (s_cand[j] > mine) ? 1 : 0;
            if (rank < MAXK) s_top[rank] = mine;
        }
    }
    __syncthreads();

    // ---- exactness guard: any thread dropped a key >= kth key? ----
    const u64 kth = s_top[K - 1];
    const int bad = (dkey >= (uint32_t)(kth >> 32)) ? 1 : 0;
    if (__syncthreads_or(bad)) {
        // rare exact fallback: rescan slice, collect all >= kth
        if (tid == 0) s_cnt = 0;
        __syncthreads();
        const int e0 = f0 << 2;
        const int e1 = f1 << 2;
        for (int e = e0 + tid; e < e1; e += K1_THREADS) {
            u64 p = ((u64)fkey(rowbase[e]) << 32) | (uint32_t)~(uint32_t)e;
            if (p >= kth) {
                int q = atomicAdd(&s_cnt, 1);
                if (q < CAND_MAX) s_cand[q] = p;
            }
        }
        __syncthreads();
        const int M2 = (s_cnt < CAND_MAX) ? s_cnt : CAND_MAX;
        for (int t = tid; t < M2; t += K1_THREADS) {
            const u64 mine = s_cand[t];
            int rank = 0;
            for (int j = 0; j < M2; ++j) rank += (s_cand[j] > mine) ? 1 : 0;
            if (rank < MAXK) s_top[rank] = mine;
        }
        __syncthreads();
    }

    if (tid < K) ws[(size_t)blockIdx.x * MAXK + tid] = s_top[tid];
}

// ============ kernel 2: merge slice top-Ks + sampler math per row ============
__global__ __launch_bounds__(256) void merge_sampler_kernel(
    const u64* __restrict__ ws,
    const float* __restrict__ temperature,
    const float* __restrict__ top_p,
    const int* __restrict__ token_lengths,
    const int* __restrict__ top_k_ptr,
    int* __restrict__ out, int V)
{
    const int row = blockIdx.x;
    const int tid = threadIdx.x;
    int K = *top_k_ptr;
    if (K < 1) K = 1;
    if (K > MAXK) K = MAXK;
    const int M = SPLIT * K;

    __shared__ u64 s_cand[SPLIT * MAXK];
    __shared__ float s_vals[MAXK];
    __shared__ int s_idx[MAXK], s_slot[MAXK];

    if (tid < M) {
        const int s = tid / K, k = tid - s * K;
        s_cand[tid] = ws[(size_t)(row * SPLIT + s) * MAXK + k];
    }
    __syncthreads();

    if (tid < M) {
        const u64 mine = s_cand[tid];
        int rank = 0;
        for (int j = 0; j < M; ++j) rank += (s_cand[j] > mine) ? 1 : 0;
        if (rank < MAXK) {
            s_idx[rank]  = (int)(~(uint32_t)mine);
            s_vals[rank] = fval((uint32_t)(mine >> 32));
        }
    }
    __syncthreads();

    // ---- single wave does the sampler math (validated R6 code) ----
    if (tid >= 64) return;          // no __syncthreads below this point

    const float temp = temperature[row];
    const float tp   = top_p[row];

    // stage 1 softmax over K scaled values (lane i owns slot i)
    const float a0 = s_vals[0] / temp;
    float e = 0.f;
    int myidx = -1;
    if (tid < K) {
        myidx = s_idx[tid];
        e = expf(s_vals[tid] / temp - a0);
    }
    float sum = e;
    #pragma unroll
    for (int off = 1; off < 64; off <<= 1) sum += __shfl_xor(sum, off, 64);
    const float p1 = e / sum;

    // suffix-inclusive cumsum: cs_i = sum_{j>=i} p1_j
    float csf = p1;
    #pragma unroll
    for (int off = 1; off < 64; off <<= 1) {
        float o = __shfl_down(csf, off, 64);
        csf += (tid + off < 64) ? o : 0.f;
    }
    const float lim = 1.0f - tp;
    const bool keep = (tid < K) && (tid == 0 || csf > lim);
    const int S = __popcll(__ballot(keep));   // survivors = descending prefix [0,S)

    // stage 2 re-softmax over survivors
    float e2 = (tid < S) ? e : 0.f;
    float sum2 = e2;
    #pragma unroll
    for (int off = 1; off < 64; off <<= 1) sum2 += __shfl_xor(sum2, off, 64);
    const float p2 = e2 / sum2;

    // EOS rule
    const bool is_eos = (tid < S) && (myidx == 2);
    float eosp = is_eos ? p2 : 0.f;
    #pragma unroll
    for (int off = 1; off < 64; off <<= 1) eosp += __shfl_xor(eosp, off, 64);
    const bool has_eos = (__ballot(is_eos) != 0ull);
    const float eth = fmaxf(eosp / 100.0f, 0.005f);

    // slot indices: survivors keep token idx; padding = smallest absent ints
    if (tid < S) s_slot[tid] = myidx;
    __builtin_amdgcn_wave_barrier();
    if (tid == 0) {
        u64 m0 = 0ull, m1 = 0ull;
        for (int i = 0; i < S; ++i) {
            int id = s_idx[i];
            if (id < 64) m0 |= 1ull << id;
            else if (id < 128) m1 |= 1ull << (id - 64);
        }
        int nxt = 0;
        for (int i = S; i < K; ++i) {
            while ((nxt < 64) ? ((m0 >> nxt) & 1ull) : ((m1 >> (nxt - 64)) & 1ull)) nxt++;
            s_slot[i] = nxt++;
        }
    }
    __builtin_amdgcn_wave_barrier();

    // length softmax over all K slots
    float len = -INFINITY;
    if (tid < K) {
        int id = s_slot[tid];
        id = (id < 0) ? 0 : ((id >= V) ? V - 1 : id);
        len = (float)token_lengths[id];
    }
    float lmax = len;
    #pragma unroll
    for (int off = 1; off < 64; off <<= 1) lmax = fmaxf(lmax, __shfl_xor(lmax, off, 64));
    float el = (tid < K) ? expf(len - lmax) : 0.f;
    float lsum = el;
    #pragma unroll
    for (int off = 1; off < 64; off <<= 1) lsum += __shfl_xor(lsum, off, 64);
    const float ls = el / lsum;

    // mix + masks + first-occurrence argmax
    float mix = -INFINITY;
    if (tid < S) {
        mix = 0.5f * p2 + 0.5f * ls;
        if (!(p2 >= 0.001f)) mix = -INFINITY;
        if (has_eos && !(p2 >= eth)) mix = -INFINITY;
    }
    float bm = mix; int bi = tid;
    #pragma unroll
    for (int off = 1; off < 64; off <<= 1) {
        float om = __shfl_xor(bm, off, 64);
        int   oi = __shfl_xor(bi, off, 64);
        if (om > bm || (om == bm && oi < bi)) { bm = om; bi = oi; }
    }

    if (tid == 0) {
        int chosen = s_slot[bi];
        if (temp < 1e-5f) chosen = s_idx[0];   // greedy branch
        out[row] = chosen;
    }
}

extern "C" void kernel_launch(void* const* d_in, const int* in_sizes, int n_in,
                              void* d_out, int out_size, void* d_ws, size_t ws_size,
                              hipStream_t stream) {
    const float* logits        = (const float*)d_in[0];
    const float* temperature   = (const float*)d_in[1];
    const float* top_p         = (const float*)d_in[2];
    const int*   token_lengths = (const int*)d_in[3];
    const int*   top_k_ptr     = (const int*)d_in[4];
    int* outp = (int*)d_out;
    u64* ws   = (u64*)d_ws;

    const int B = in_sizes[1];   // temperature length
    const int V = in_sizes[3];   // token_lengths length

    topk_slice_kernel<<<B * SPLIT, K1_THREADS, 0, stream>>>(logits, top_k_ptr, ws, V);
    merge_sampler_kernel<<<B, 256, 0, stream>>>(ws, temperature, top_p,
                                                token_lengths, top_k_ptr, outp, V);
}